// Round 12
// baseline (206.764 us; speedup 1.0000x reference)
//
#include <hip/hip_runtime.h>
#include <hip/hip_fp16.h>

#define NB 8
#define NC 256
#define NHW 1024
#define NI 8
#define NH 4
#define HD 64
#define EPS 1e-12f
#define QSC  64.0f
#define QSCI 0.015625f
#define QSCL 0.02254211001389006f   // QSCI * log2(e)

typedef _Float16 f16;
typedef __attribute__((ext_vector_type(8))) _Float16 half8;
typedef __attribute__((ext_vector_type(4))) float floatx4;

union H8 { half8 h8; __half2 h2[4]; uint4 u4; f16 e[8]; };
union H4 { uint2 u2; __half2 h2[2]; f16 e[4]; };
union PK { __half2 h2; unsigned u; };

__device__ __forceinline__ void gll16(const void* g, void* l) {
    __builtin_amdgcn_global_load_lds(
        (const __attribute__((address_space(1))) unsigned int*)g,
        (__attribute__((address_space(3))) unsigned int*)l, 16, 0, 0);
}

// ---------------- K1: mask logit partials + xt emit (v12: SGPR weights, full-unroll MLP) ----------------
__global__ __launch_bounds__(256) void k_mask_part(
    const float* __restrict__ x, const float* __restrict__ w_inst,
    float* __restrict__ part_m, f16* __restrict__ xt)
{
    __shared__ __align__(16) f16 xls[32][264];
    int nt = blockIdx.x, b = blockIdx.y, cc = blockIdx.z;
    int tid = threadIdx.x;
    int n = nt*256 + tid;
    const float* xp = x + ((size_t)(b*NC + cc*32))*NHW + n;
    const float* wp = w_inst + cc*32;
    float acc[NI] = {};
#pragma unroll
    for (int c = 0; c < 32; ++c) {
        float xv = xp[(size_t)c*NHW];
        xls[c][tid] = (f16)xv;
#pragma unroll
        for (int i = 0; i < NI; ++i) acc[i] = fmaf(wp[i*NC + c], xv, acc[i]);
    }
#pragma unroll
    for (int i = 0; i < NI; ++i)
        part_m[((size_t)(cc*NI + i)*NB + b)*NHW + n] = acc[i];
    __syncthreads();
#pragma unroll
    for (int it = 0; it < 4; ++it) {
        int r = (tid >> 2) + it*64;
        int c8 = (tid & 3)*8;
        H8 v;
#pragma unroll
        for (int i = 0; i < 8; ++i) v.e[i] = xls[c8 + i][r];
        *(uint4*)(xt + ((size_t)(b*NHW + nt*256 + r))*NC + cc*32 + c8) = v.u4;
    }
}

// ---------------- K2: MFMA f16 GEMM G = W*x, W cast inline (768 blocks) ----------------
__global__ __launch_bounds__(256) void k_gemm_mfma(
    const f16* __restrict__ xt,
    const float* __restrict__ wq, const float* __restrict__ wk, const float* __restrict__ wv,
    f16* __restrict__ Gqt, f16* __restrict__ Gkt, f16* __restrict__ Gv)
{
    __shared__ __align__(16) char glds[30720];
    int tid = threadIdx.x;
    int nt = blockIdx.x, ot = blockIdx.y;
    int m = blockIdx.z >> 3, b = blockIdx.z & 7;
    const float* wsel = (m == 0) ? wq : (m == 1) ? wk : wv;
    int o0 = ot*64;
    int w = tid >> 6, lane = tid & 63, quad = lane >> 4, l15 = lane & 15;
    const f16* xb = xt + (size_t)b*NHW*NC + (size_t)nt*128*NC;
    f16* wt0 = (f16*)glds;                       // [2][64][40]
    f16* xt0 = (f16*)(glds + 10240);             // [2][128][40]
    int srow = tid >> 2, scol = (tid & 3)*8;

    floatx4 acc[2][4];
#pragma unroll
    for (int nm=0;nm<2;nm++)
#pragma unroll
        for (int om=0;om<4;om++){ acc[nm][om][0]=0.f; acc[nm][om][1]=0.f;
                                  acc[nm][om][2]=0.f; acc[nm][om][3]=0.f; }
    {   // stage k=0 into buf 0 (cast W fp32->f16 inline)
        float4 a4 = *(const float4*)(wsel + (size_t)(o0+srow)*NC + scol);
        float4 b4 = *(const float4*)(wsel + (size_t)(o0+srow)*NC + scol + 4);
        H8 hw;
        hw.h2[0] = __floats2half2_rn(a4.x, a4.y); hw.h2[1] = __floats2half2_rn(a4.z, a4.w);
        hw.h2[2] = __floats2half2_rn(b4.x, b4.y); hw.h2[3] = __floats2half2_rn(b4.z, b4.w);
        *(uint4*)&wt0[(0*64 + srow)*40 + scol] = hw.u4;
        *(uint4*)&xt0[(0*128 + srow)*40 + scol]    = *(const uint4*)(xb + (size_t)srow*NC + scol);
        *(uint4*)&xt0[(0*128 + 64+srow)*40 + scol] = *(const uint4*)(xb + (size_t)(64+srow)*NC + scol);
    }
    for (int k = 0; k < 8; ++k) {
        int p = k & 1;
        __syncthreads();
        if (k < 7) {
            int q = 1 - p, kc = (k+1)*32;
            float4 a4 = *(const float4*)(wsel + (size_t)(o0+srow)*NC + kc + scol);
            float4 b4 = *(const float4*)(wsel + (size_t)(o0+srow)*NC + kc + scol + 4);
            H8 hw;
            hw.h2[0] = __floats2half2_rn(a4.x, a4.y); hw.h2[1] = __floats2half2_rn(a4.z, a4.w);
            hw.h2[2] = __floats2half2_rn(b4.x, b4.y); hw.h2[3] = __floats2half2_rn(b4.z, b4.w);
            *(uint4*)&wt0[(q*64 + srow)*40 + scol] = hw.u4;
            *(uint4*)&xt0[(q*128 + srow)*40 + scol]    = *(const uint4*)(xb + (size_t)srow*NC + kc + scol);
            *(uint4*)&xt0[(q*128 + 64+srow)*40 + scol] = *(const uint4*)(xb + (size_t)(64+srow)*NC + kc + scol);
        }
        H8 wa[4], xa[2];
#pragma unroll
        for (int om = 0; om < 4; ++om)
            wa[om].u4 = *(const uint4*)&wt0[(p*64 + om*16 + l15)*40 + quad*8];
#pragma unroll
        for (int nm = 0; nm < 2; ++nm)
            xa[nm].u4 = *(const uint4*)&xt0[(p*128 + w*32 + nm*16 + l15)*40 + quad*8];
#pragma unroll
        for (int nm = 0; nm < 2; ++nm)
#pragma unroll
            for (int om = 0; om < 4; ++om)
                acc[nm][om] = __builtin_amdgcn_mfma_f32_16x16x32_f16(wa[om].h8, xa[nm].h8, acc[nm][om], 0, 0, 0);
    }
    __syncthreads();
    if (m < 2) {
        f16* lt = (f16*)glds;   // [128][72]
#pragma unroll
        for (int nm = 0; nm < 2; ++nm)
#pragma unroll
            for (int om = 0; om < 4; ++om) {
                H4 pk;
#pragma unroll
                for (int r = 0; r < 4; ++r) pk.e[r] = (f16)acc[nm][om][r];
                *(uint2*)&lt[(size_t)(w*32 + nm*16 + l15)*72 + om*16 + quad*4] = pk.u2;
            }
        __syncthreads();
        f16* dst = (m == 0) ? Gqt : Gkt;
#pragma unroll
        for (int it = 0; it < 4; ++it) {
            int row = (tid >> 3) + it*32;
            int c8 = (tid & 7)*8;
            uint4 v = *(const uint4*)&lt[(size_t)row*72 + c8];
            *(uint4*)(dst + ((size_t)(b*NHW + nt*128 + row))*NC + o0 + c8) = v;
        }
    } else {
        f16* lv = (f16*)glds;   // [64][136]
#pragma unroll
        for (int nm = 0; nm < 2; ++nm)
#pragma unroll
            for (int om = 0; om < 4; ++om)
#pragma unroll
                for (int r = 0; r < 4; ++r)
                    lv[(size_t)(om*16 + quad*4 + r)*136 + w*32 + nm*16 + l15] = (f16)acc[nm][om][r];
        __syncthreads();
#pragma unroll
        for (int it = 0; it < 4; ++it) {
            int row = (tid >> 4) + it*16;
            int n8 = (tid & 15)*8;
            uint4 v = *(const uint4*)&lv[(size_t)row*136 + n8];
            *(uint4*)(Gv + ((size_t)(b*NC + o0 + row))*NHW + nt*128 + n8) = v;
        }
    }
}

// ---------------- K3: fused mask-softmax + norm partials (v12: t4-blocked, full-unroll MLP) ----------------
__global__ __launch_bounds__(256) void k_norm_mask(
    const float* __restrict__ part_m, const float* __restrict__ b_inst,
    const f16* __restrict__ Gqt, const f16* __restrict__ Gkt,
    const float* __restrict__ bq, const float* __restrict__ bk,
    float* __restrict__ masks, float* __restrict__ part_nq, float* __restrict__ part_nk)
{
    __shared__ float lg[NI][32];
    __shared__ __align__(16) float m_s[NI][32];
    int nc = blockIdx.x, b = blockIdx.y;
    int tid = threadIdx.x;
    int n0 = nc*32;
    {
        int nl = tid & 31, i = tid >> 5;
        float s = b_inst[i];
#pragma unroll
        for (int cc = 0; cc < 8; ++cc)
            s += part_m[((size_t)(cc*NI + i)*NB + b)*NHW + n0 + nl];
        lg[i][nl] = s;
    }
    __syncthreads();
    {
        int nl = tid & 31, i = tid >> 5;
        float mx = lg[0][nl];
#pragma unroll
        for (int k = 1; k < NI; ++k) mx = fmaxf(mx, lg[k][nl]);
        float ssum = 0.f;
#pragma unroll
        for (int k = 0; k < NI; ++k) ssum += __expf(lg[k][nl] - mx);
        float mv = __expf(lg[i][nl] - mx) / ssum;
        m_s[i][nl] = mv;
        masks[((size_t)i*NB + b)*NHW + n0 + nl] = mv;
    }
    __syncthreads();
    int c = tid;
    float bqv = bq[c], bkv = bk[c];
    const f16* gq = Gqt + ((size_t)b*NHW + n0)*NC + c;
    const f16* gk = Gkt + ((size_t)b*NHW + n0)*NC + c;
    float aq[NI] = {}, ak[NI] = {};
#pragma unroll
    for (int t4 = 0; t4 < 32; t4 += 4) {
        float g1[4], g2[4];
#pragma unroll
        for (int r = 0; r < 4; ++r) {
            g1[r] = (float)gq[(size_t)(t4 + r)*NC];
            g2[r] = (float)gk[(size_t)(t4 + r)*NC];
        }
#pragma unroll
        for (int i = 0; i < NI; ++i) {
            float4 mm4 = *(const float4*)&m_s[i][t4];
            float mm[4] = {mm4.x, mm4.y, mm4.z, mm4.w};
#pragma unroll
            for (int r = 0; r < 4; ++r) {
                float e = fmaf(mm[r], g1[r], bqv); aq[i] = fmaf(e, e, aq[i]);
                e = fmaf(mm[r], g2[r], bkv);       ak[i] = fmaf(e, e, ak[i]);
            }
        }
    }
#pragma unroll
    for (int i = 0; i < NI; ++i) {
        part_nq[((size_t)(nc*NI + i)*NB + b)*NC + c] = aq[i];
        part_nk[((size_t)(nc*NI + i)*NB + b)*NC + c] = ak[i];
    }
}

// ---------------- K3b: finalize scales (v15 split: grid (8,8,4) x 64 thr — all 256 CUs busy) ----------------
__global__ __launch_bounds__(64) void k_norm_fin(
    const float* __restrict__ part_nq, const float* __restrict__ part_nk,
    float* __restrict__ scale_q, float* __restrict__ scale_k)
{
    int b = blockIdx.x, i = blockIdx.y;
    int c = blockIdx.z*64 + threadIdx.x;
    float sq = 0.f, sk = 0.f;
#pragma unroll
    for (int nc = 0; nc < 32; ++nc) {
        sq += part_nq[((size_t)(nc*NI + i)*NB + b)*NC + c];
        sk += part_nk[((size_t)(nc*NI + i)*NB + b)*NC + c];
    }
    scale_q[((size_t)i*NB + b)*NC + c] = 0.125f / fmaxf(sqrtf(sq), EPS);
    scale_k[((size_t)i*NB + b)*NC + c] = 1.0f   / fmaxf(sqrtf(sk), EPS);
}

// ---------------- K4: attention v18 = v11 + exp2-fold (issue diet on the softmax path) ----------------
// Attn is issue-bound (dur invariant to occupancy 19-38%, DS 0.5-2x, wave count). Fold the
// __expf-internal mul-by-log2(e) into the per-r mask factor: mjq = mj*(QSCI*log2e), then
// exp2 directly — saves 64 v_mul issues per wave-iter + 1 op off the exp dep chain.
// Everything else identical to v11 (112.3-113.5 µs measured).
__global__ __launch_bounds__(256,2) void k_attn18(
    const f16* __restrict__ Gqt, const f16* __restrict__ Gkt, const f16* __restrict__ Gv,
    const float* __restrict__ masks,
    const float* __restrict__ bq, const float* __restrict__ bv,
    const float* __restrict__ scale_q, const float* __restrict__ scale_k,
    float* __restrict__ out)
{
    __shared__ __align__(16) char lds[38912];
    f16*   KH = (f16*)lds;
    f16*   VH = (f16*)(lds + 16384);
    float* MI = (float*)(lds + 32768);

    int tid = threadIdx.x, bid = blockIdx.x;
    int b = bid & 7, qt = (bid >> 3) & 31, h = bid >> 8;
    int qt0 = qt*32, c0 = h*HD;
    int w = tid >> 6, lane = tid & 63, quad = lane >> 4, l15 = lane & 15;
    int i0 = 2*w;

    // ---- hoisted raw Gq B-frags + per-instance q~ (mask/bias/scales, x64) ----
    H8 graw[2][2];
    const f16* gqp = Gqt + ((size_t)b*NHW + qt0)*NC + c0;
#pragma unroll
    for (int qi = 0; qi < 2; ++qi)
#pragma unroll
        for (int ks = 0; ks < 2; ++ks)
            graw[qi][ks].u4 = *(const uint4*)(gqp + (size_t)(qi*16 + l15)*NC + ks*32 + quad*8);
    float mqf[2][2];
#pragma unroll
    for (int ii = 0; ii < 2; ++ii)
#pragma unroll
        for (int qi = 0; qi < 2; ++qi)
            mqf[ii][qi] = masks[((size_t)(i0+ii)*NB + b)*NHW + qt0 + qi*16 + l15];
    H8 qa[2][2][2];
#pragma unroll
    for (int ks = 0; ks < 2; ++ks) {
        int cb = c0 + ks*32 + quad*8;
        float4 bq0 = *(const float4*)(bq + cb);
        float4 bq1 = *(const float4*)(bq + cb + 4);
#pragma unroll
        for (int ii = 0; ii < 2; ++ii) {
            int inst = i0 + ii;
            const float* sqg = scale_q + ((size_t)inst*NB + b)*NC;
            const float* skg = scale_k + ((size_t)inst*NB + b)*NC;
            float4 s0 = *(const float4*)(sqg + cb);
            float4 s1 = *(const float4*)(sqg + cb + 4);
            float4 t0 = *(const float4*)(skg + cb);
            float4 t1 = *(const float4*)(skg + cb + 4);
            float ss[8] = {s0.x*t0.x*QSC, s0.y*t0.y*QSC, s0.z*t0.z*QSC, s0.w*t0.w*QSC,
                           s1.x*t1.x*QSC, s1.y*t1.y*QSC, s1.z*t1.z*QSC, s1.w*t1.w*QSC};
            float bb[8] = {bq0.x*ss[0], bq0.y*ss[1], bq0.z*ss[2], bq0.w*ss[3],
                           bq1.x*ss[4], bq1.y*ss[5], bq1.z*ss[6], bq1.w*ss[7]};
            __half2 sh[4], bh[4];
#pragma unroll
            for (int t = 0; t < 4; ++t) {
                sh[t] = __floats2half2_rn(ss[2*t], ss[2*t+1]);
                bh[t] = __floats2half2_rn(bb[2*t], bb[2*t+1]);
            }
#pragma unroll
            for (int qi = 0; qi < 2; ++qi) {
                __half2 mq2 = __float2half2_rn(mqf[ii][qi]);
#pragma unroll
                for (int t = 0; t < 4; ++t)
                    qa[ii][qi][ks].h2[t] = __hfma2(mq2, __hmul2(graw[qi][ks].h2[t], sh[t]), bh[t]);
            }
        }
    }

    // ---- staging lane constants (pre-swizzled global source, linear LDS dest) ----
    int kjr = tid >> 3, kdc = (tid & 7) ^ (kjr & 7);
    const f16* kgb = Gkt + (size_t)b*NHW*NC + c0 + kdc*8;      // + (jn+row)*NC
    int vcr = tid >> 3, vdc = (tid & 7) ^ (vcr & 7);
    const f16* vgb = Gv + ((size_t)(b*NC + c0 + vcr))*NHW + vdc*8;   // + jn
    const float* mgb = masks + ((size_t)(tid >> 4)*NB + b)*NHW + (tid & 15)*4;

    floatx4 acc[2][4][2];
#pragma unroll
    for (int ii=0;ii<2;ii++)
#pragma unroll
        for (int cm=0;cm<4;cm++)
#pragma unroll
            for (int qi=0;qi<2;qi++) { acc[ii][cm][qi][0]=0.f; acc[ii][cm][qi][1]=0.f;
                                       acc[ii][cm][qi][2]=0.f; acc[ii][cm][qi][3]=0.f; }
    float l[2][2] = {};

    // prologue: stage tile 0 -> buf 0 (async)
    gll16(kgb + (size_t)kjr*NC,        KH + tid*8);
    gll16(kgb + (size_t)(32+kjr)*NC,   KH + 2048 + tid*8);
    gll16(vgb,                          VH + tid*8);
    gll16(vgb + (size_t)32*NHW,         VH + 2048 + tid*8);
    if (tid < 128) gll16(mgb, MI + tid*4);
    __syncthreads();

    int p = 0;
    for (int j0 = 0; j0 < NHW; j0 += 64) {
        int jn = (j0 + 64) & (NHW - 1);
        // async stage next tile -> buf p^1 (buf strides: KH/VH 4096 f16, MI 512 f32)
        {
            f16* khn = KH + (p^1)*4096;
            f16* vhn = VH + (p^1)*4096;
            gll16(kgb + (size_t)(jn + kjr)*NC,      khn + tid*8);
            gll16(kgb + (size_t)(jn + 32 + kjr)*NC, khn + 2048 + tid*8);
            gll16(vgb + jn,                          vhn + tid*8);
            gll16(vgb + (size_t)32*NHW + jn,         vhn + 2048 + tid*8);
            if (tid < 128) gll16(mgb + jn, MI + (p^1)*512 + tid*4);
        }

        const f16* kh = KH + p*4096;
        const f16* vh = VH + p*4096;
        const float* mi = MI + p*512;

        // ---- per 32-j half: QK scores -> softmax -> pb -> PV (pb live range = 1 half) ----
#pragma unroll
        for (int half = 0; half < 2; ++half) {
            unsigned pw[2][2][2][2];   // [ii][qi][jm2][pair]
#pragma unroll
            for (int jm2 = 0; jm2 < 2; ++jm2) {
                int jm = half*2 + jm2;
                int krow = jm*16 + l15;
                H8 ka0, ka1;
                ka0.u4 = *(const uint4*)&kh[krow*64 + ((quad       ^ (l15 & 7))*8)];
                ka1.u4 = *(const uint4*)&kh[krow*64 + (((4 + quad) ^ (l15 & 7))*8)];
#pragma unroll
                for (int ii = 0; ii < 2; ++ii) {
                    floatx4 s0 = {0.f,0.f,0.f,0.f}, s1 = {0.f,0.f,0.f,0.f};
                    s0 = __builtin_amdgcn_mfma_f32_16x16x32_f16(ka0.h8, qa[ii][0][0].h8, s0, 0, 0, 0);
                    s0 = __builtin_amdgcn_mfma_f32_16x16x32_f16(ka1.h8, qa[ii][0][1].h8, s0, 0, 0, 0);
                    s1 = __builtin_amdgcn_mfma_f32_16x16x32_f16(ka0.h8, qa[ii][1][0].h8, s1, 0, 0, 0);
                    s1 = __builtin_amdgcn_mfma_f32_16x16x32_f16(ka1.h8, qa[ii][1][1].h8, s1, 0, 0, 0);
                    float4 mj4 = *(const float4*)&mi[(i0+ii)*64 + jm*16 + quad*4];
                    float mj[4] = {mj4.x, mj4.y, mj4.z, mj4.w};
                    float p0[4], p1[4];
#pragma unroll
                    for (int r = 0; r < 4; ++r) {
                        float mjq = mj[r]*QSCL;   // folds expf's mul-by-log2e
                        float e0 = __builtin_amdgcn_exp2f(s0[r]*mjq); l[ii][0] += e0; p0[r] = e0*mj[r];
                        float e1 = __builtin_amdgcn_exp2f(s1[r]*mjq); l[ii][1] += e1; p1[r] = e1*mj[r];
                    }
                    PK k0, k1, k2, k3;
                    k0.h2 = __floats2half2_rn(p0[0], p0[1]); k1.h2 = __floats2half2_rn(p0[2], p0[3]);
                    k2.h2 = __floats2half2_rn(p1[0], p1[1]); k3.h2 = __floats2half2_rn(p1[2], p1[3]);
                    pw[ii][0][jm2][0] = k0.u; pw[ii][0][jm2][1] = k1.u;
                    pw[ii][1][jm2][0] = k2.u; pw[ii][1][jm2][1] = k3.u;
                }
            }
            // D-layout -> B-layout quad redistribution (v9-verified):
            // (u0,u2) = p16swap(p32swap(w0,w2)); (u1,u3) = p16swap(p32swap(w1,w3))
            H8 pb[2][2];
#pragma unroll
            for (int ii = 0; ii < 2; ++ii)
#pragma unroll
                for (int qi = 0; qi < 2; ++qi) {
                    unsigned a = pw[ii][qi][0][0], bx = pw[ii][qi][0][1];
                    unsigned c = pw[ii][qi][1][0], d  = pw[ii][qi][1][1];
                    asm("v_permlane32_swap_b32 %0, %1" : "+v"(a),  "+v"(c));
                    asm("v_permlane16_swap_b32 %0, %1" : "+v"(a),  "+v"(c));
                    asm("v_permlane32_swap_b32 %0, %1" : "+v"(bx), "+v"(d));
                    asm("v_permlane16_swap_b32 %0, %1" : "+v"(bx), "+v"(d));
                    H8 t; t.u4.x = a; t.u4.y = bx; t.u4.z = c; t.u4.w = d;
                    pb[ii][qi] = t;
                }
            // ---- PV for this half: chunk (half*4+quad) ^ (l15&7) ----
#pragma unroll
            for (int cm = 0; cm < 4; ++cm) {
                H8 va;
                va.u4 = *(const uint4*)&vh[(cm*16 + l15)*64 + (((half*4 + quad) ^ (l15 & 7))*8)];
                acc[0][cm][0] = __builtin_amdgcn_mfma_f32_16x16x32_f16(va.h8, pb[0][0].h8, acc[0][cm][0], 0, 0, 0);
                acc[0][cm][1] = __builtin_amdgcn_mfma_f32_16x16x32_f16(va.h8, pb[0][1].h8, acc[0][cm][1], 0, 0, 0);
                acc[1][cm][0] = __builtin_amdgcn_mfma_f32_16x16x32_f16(va.h8, pb[1][0].h8, acc[1][cm][0], 0, 0, 0);
                acc[1][cm][1] = __builtin_amdgcn_mfma_f32_16x16x32_f16(va.h8, pb[1][1].h8, acc[1][cm][1], 0, 0, 0);
            }
        }
        __syncthreads();   // drains gll (next tile ready) + fences buffer reuse
        p ^= 1;
    }

    // ---- f = m_q/l (reduce over quads: lane bits 4,5) ----
    float f[2][2];
#pragma unroll
    for (int ii = 0; ii < 2; ++ii)
#pragma unroll
        for (int qi = 0; qi < 2; ++qi) {
            float lv = l[ii][qi];
            lv += __shfl_xor(lv, 16, 64);
            lv += __shfl_xor(lv, 32, 64);
            f[ii][qi] = mqf[ii][qi] / lv;
        }
    // ---- cross-instance 2-phase tree (overlay on KH region, dead after loop) ----
    float* bufA = (float*)lds;
    float* bufB = bufA + 2304;
    if (w < 2) {
        float* rb = w ? bufB : bufA;
#pragma unroll
        for (int cm = 0; cm < 4; ++cm)
#pragma unroll
            for (int qi = 0; qi < 2; ++qi)
#pragma unroll
                for (int r = 0; r < 4; ++r)
                    rb[(cm*16 + quad*4 + r)*36 + qi*16 + l15] =
                        f[0][qi]*acc[0][cm][qi][r] + f[1][qi]*acc[1][cm][qi][r];
    }
    __syncthreads();
    if (w >= 2) {
        float* rb = (w == 3) ? bufB : bufA;
#pragma unroll
        for (int cm = 0; cm < 4; ++cm)
#pragma unroll
            for (int qi = 0; qi < 2; ++qi)
#pragma unroll
                for (int r = 0; r < 4; ++r)
                    rb[(cm*16 + quad*4 + r)*36 + qi*16 + l15] +=
                        f[0][qi]*acc[0][cm][qi][r] + f[1][qi]*acc[1][cm][qi][r];
    }
    __syncthreads();
    int cc2 = tid >> 2, qg = (tid & 3)*8;
    float bvv = bv[c0 + cc2];
    float* op = out + ((size_t)(b*NC + c0 + cc2))*NHW + qt0;
#pragma unroll
    for (int t = 0; t < 2; ++t) {
        float4 va4 = *(const float4*)&bufA[cc2*36 + qg + t*4];
        float4 vb4 = *(const float4*)&bufB[cc2*36 + qg + t*4];
        float4 v;
        v.x = va4.x + vb4.x + bvv; v.y = va4.y + vb4.y + bvv;
        v.z = va4.z + vb4.z + bvv; v.w = va4.w + vb4.w + bvv;
        *(float4*)(op + qg + t*4) = v;
    }
}

extern "C" void kernel_launch(void* const* d_in, const int* in_sizes, int n_in,
                              void* d_out, int out_size, void* d_ws, size_t ws_size,
                              hipStream_t stream)
{
    const float* x      = (const float*)d_in[0];
    const float* w_inst = (const float*)d_in[1];
    const float* b_inst = (const float*)d_in[2];
    const float* wq = (const float*)d_in[3];
    const float* bq = (const float*)d_in[4];
    const float* wk = (const float*)d_in[5];
    const float* bk = (const float*)d_in[6];
    const float* wv = (const float*)d_in[7];
    const float* bv = (const float*)d_in[8];
    float* out = (float*)d_out;

    float* masks   = (float*)d_ws;                        // 8*8*1024 f32
    float* scale_q = masks + (size_t)NI*NB*NHW;           // 8*8*256
    float* scale_k = scale_q + (size_t)NI*NB*NC;
    f16*   Gqt     = (f16*)(scale_k + (size_t)NI*NB*NC);  // [b][n][c] f16
    f16*   Gkt     = Gqt + (size_t)NB*NHW*NC;             // [b][n][c] f16
    f16*   Gv      = Gkt + (size_t)NB*NHW*NC;             // [b][c][n] f16
    f16*   xt      = Gv + (size_t)NB*NC*NHW;              // [b][n][c] f16
    float* part_m  = (float*)(xt + (size_t)NB*NHW*NC);    // 8*8*8*1024
    float* part_nq = part_m + (size_t)8*NI*NB*NHW;        // 32*8*8*256
    float* part_nk = part_nq + (size_t)32*NI*NB*NC;

    k_mask_part<<<dim3(4, NB, 8), 256, 0, stream>>>(x, w_inst, part_m, xt);
    k_gemm_mfma<<<dim3(8, 4, 24), 256, 0, stream>>>(xt, wq, wk, wv, Gqt, Gkt, Gv);
    k_norm_mask<<<dim3(32, NB), 256, 0, stream>>>(part_m, b_inst, Gqt, Gkt, bq, bk,
                                                  masks, part_nq, part_nk);
    k_norm_fin<<<dim3(NB, NI, 4), 64, 0, stream>>>(part_nq, part_nk, scale_q, scale_k);
    k_attn18<<<dim3(1024), 256, 0, stream>>>(Gqt, Gkt, Gv, masks, bq, bv,
                                             scale_q, scale_k, out);
}

// Round 13
// 202.562 us; speedup vs baseline: 1.0207x; 1.0207x over previous
//
#include <hip/hip_runtime.h>
#include <hip/hip_fp16.h>

#define NB 8
#define NC 256
#define NHW 1024
#define NI 8
#define NH 4
#define HD 64
#define EPS 1e-12f
#define QSC  64.0f
#define QSCI 0.015625f

typedef _Float16 f16;
typedef __attribute__((ext_vector_type(8))) _Float16 half8;
typedef __attribute__((ext_vector_type(4))) float floatx4;

union H8 { half8 h8; __half2 h2[4]; uint4 u4; f16 e[8]; };
union H4 { uint2 u2; __half2 h2[2]; f16 e[4]; };
union PK { __half2 h2; unsigned u; };

__device__ __forceinline__ void gll16(const void* g, void* l) {
    __builtin_amdgcn_global_load_lds(
        (const __attribute__((address_space(1))) unsigned int*)g,
        (__attribute__((address_space(3))) unsigned int*)l, 16, 0, 0);
}

// ---------------- K1: mask logit partials + xt emit (v12: SGPR weights, full-unroll MLP) ----------------
__global__ __launch_bounds__(256) void k_mask_part(
    const float* __restrict__ x, const float* __restrict__ w_inst,
    float* __restrict__ part_m, f16* __restrict__ xt)
{
    __shared__ __align__(16) f16 xls[32][264];
    int nt = blockIdx.x, b = blockIdx.y, cc = blockIdx.z;
    int tid = threadIdx.x;
    int n = nt*256 + tid;
    const float* xp = x + ((size_t)(b*NC + cc*32))*NHW + n;
    const float* wp = w_inst + cc*32;
    float acc[NI] = {};
#pragma unroll
    for (int c = 0; c < 32; ++c) {
        float xv = xp[(size_t)c*NHW];
        xls[c][tid] = (f16)xv;
#pragma unroll
        for (int i = 0; i < NI; ++i) acc[i] = fmaf(wp[i*NC + c], xv, acc[i]);
    }
#pragma unroll
    for (int i = 0; i < NI; ++i)
        part_m[((size_t)(cc*NI + i)*NB + b)*NHW + n] = acc[i];
    __syncthreads();
#pragma unroll
    for (int it = 0; it < 4; ++it) {
        int r = (tid >> 2) + it*64;
        int c8 = (tid & 3)*8;
        H8 v;
#pragma unroll
        for (int i = 0; i < 8; ++i) v.e[i] = xls[c8 + i][r];
        *(uint4*)(xt + ((size_t)(b*NHW + nt*256 + r))*NC + cc*32 + c8) = v.u4;
    }
}

// ---------------- K2: MFMA f16 GEMM G = W*x, W cast inline (768 blocks) ----------------
__global__ __launch_bounds__(256) void k_gemm_mfma(
    const f16* __restrict__ xt,
    const float* __restrict__ wq, const float* __restrict__ wk, const float* __restrict__ wv,
    f16* __restrict__ Gqt, f16* __restrict__ Gkt, f16* __restrict__ Gv)
{
    __shared__ __align__(16) char glds[30720];
    int tid = threadIdx.x;
    int nt = blockIdx.x, ot = blockIdx.y;
    int m = blockIdx.z >> 3, b = blockIdx.z & 7;
    const float* wsel = (m == 0) ? wq : (m == 1) ? wk : wv;
    int o0 = ot*64;
    int w = tid >> 6, lane = tid & 63, quad = lane >> 4, l15 = lane & 15;
    const f16* xb = xt + (size_t)b*NHW*NC + (size_t)nt*128*NC;
    f16* wt0 = (f16*)glds;                       // [2][64][40]
    f16* xt0 = (f16*)(glds + 10240);             // [2][128][40]
    int srow = tid >> 2, scol = (tid & 3)*8;

    floatx4 acc[2][4];
#pragma unroll
    for (int nm=0;nm<2;nm++)
#pragma unroll
        for (int om=0;om<4;om++){ acc[nm][om][0]=0.f; acc[nm][om][1]=0.f;
                                  acc[nm][om][2]=0.f; acc[nm][om][3]=0.f; }
    {   // stage k=0 into buf 0 (cast W fp32->f16 inline)
        float4 a4 = *(const float4*)(wsel + (size_t)(o0+srow)*NC + scol);
        float4 b4 = *(const float4*)(wsel + (size_t)(o0+srow)*NC + scol + 4);
        H8 hw;
        hw.h2[0] = __floats2half2_rn(a4.x, a4.y); hw.h2[1] = __floats2half2_rn(a4.z, a4.w);
        hw.h2[2] = __floats2half2_rn(b4.x, b4.y); hw.h2[3] = __floats2half2_rn(b4.z, b4.w);
        *(uint4*)&wt0[(0*64 + srow)*40 + scol] = hw.u4;
        *(uint4*)&xt0[(0*128 + srow)*40 + scol]    = *(const uint4*)(xb + (size_t)srow*NC + scol);
        *(uint4*)&xt0[(0*128 + 64+srow)*40 + scol] = *(const uint4*)(xb + (size_t)(64+srow)*NC + scol);
    }
    for (int k = 0; k < 8; ++k) {
        int p = k & 1;
        __syncthreads();
        if (k < 7) {
            int q = 1 - p, kc = (k+1)*32;
            float4 a4 = *(const float4*)(wsel + (size_t)(o0+srow)*NC + kc + scol);
            float4 b4 = *(const float4*)(wsel + (size_t)(o0+srow)*NC + kc + scol + 4);
            H8 hw;
            hw.h2[0] = __floats2half2_rn(a4.x, a4.y); hw.h2[1] = __floats2half2_rn(a4.z, a4.w);
            hw.h2[2] = __floats2half2_rn(b4.x, b4.y); hw.h2[3] = __floats2half2_rn(b4.z, b4.w);
            *(uint4*)&wt0[(q*64 + srow)*40 + scol] = hw.u4;
            *(uint4*)&xt0[(q*128 + srow)*40 + scol]    = *(const uint4*)(xb + (size_t)srow*NC + kc + scol);
            *(uint4*)&xt0[(q*128 + 64+srow)*40 + scol] = *(const uint4*)(xb + (size_t)(64+srow)*NC + kc + scol);
        }
        H8 wa[4], xa[2];
#pragma unroll
        for (int om = 0; om < 4; ++om)
            wa[om].u4 = *(const uint4*)&wt0[(p*64 + om*16 + l15)*40 + quad*8];
#pragma unroll
        for (int nm = 0; nm < 2; ++nm)
            xa[nm].u4 = *(const uint4*)&xt0[(p*128 + w*32 + nm*16 + l15)*40 + quad*8];
#pragma unroll
        for (int nm = 0; nm < 2; ++nm)
#pragma unroll
            for (int om = 0; om < 4; ++om)
                acc[nm][om] = __builtin_amdgcn_mfma_f32_16x16x32_f16(wa[om].h8, xa[nm].h8, acc[nm][om], 0, 0, 0);
    }
    __syncthreads();
    if (m < 2) {
        f16* lt = (f16*)glds;   // [128][72]
#pragma unroll
        for (int nm = 0; nm < 2; ++nm)
#pragma unroll
            for (int om = 0; om < 4; ++om) {
                H4 pk;
#pragma unroll
                for (int r = 0; r < 4; ++r) pk.e[r] = (f16)acc[nm][om][r];
                *(uint2*)&lt[(size_t)(w*32 + nm*16 + l15)*72 + om*16 + quad*4] = pk.u2;
            }
        __syncthreads();
        f16* dst = (m == 0) ? Gqt : Gkt;
#pragma unroll
        for (int it = 0; it < 4; ++it) {
            int row = (tid >> 3) + it*32;
            int c8 = (tid & 7)*8;
            uint4 v = *(const uint4*)&lt[(size_t)row*72 + c8];
            *(uint4*)(dst + ((size_t)(b*NHW + nt*128 + row))*NC + o0 + c8) = v;
        }
    } else {
        f16* lv = (f16*)glds;   // [64][136]
#pragma unroll
        for (int nm = 0; nm < 2; ++nm)
#pragma unroll
            for (int om = 0; om < 4; ++om)
#pragma unroll
                for (int r = 0; r < 4; ++r)
                    lv[(size_t)(om*16 + quad*4 + r)*136 + w*32 + nm*16 + l15] = (f16)acc[nm][om][r];
        __syncthreads();
#pragma unroll
        for (int it = 0; it < 4; ++it) {
            int row = (tid >> 4) + it*16;
            int n8 = (tid & 15)*8;
            uint4 v = *(const uint4*)&lv[(size_t)row*136 + n8];
            *(uint4*)(Gv + ((size_t)(b*NC + o0 + row))*NHW + nt*128 + n8) = v;
        }
    }
}

// ---------------- K3: fused mask-softmax + norm partials (v12: t4-blocked, full-unroll MLP) ----------------
__global__ __launch_bounds__(256) void k_norm_mask(
    const float* __restrict__ part_m, const float* __restrict__ b_inst,
    const f16* __restrict__ Gqt, const f16* __restrict__ Gkt,
    const float* __restrict__ bq, const float* __restrict__ bk,
    float* __restrict__ masks, float* __restrict__ part_nq, float* __restrict__ part_nk)
{
    __shared__ float lg[NI][32];
    __shared__ __align__(16) float m_s[NI][32];
    int nc = blockIdx.x, b = blockIdx.y;
    int tid = threadIdx.x;
    int n0 = nc*32;
    {
        int nl = tid & 31, i = tid >> 5;
        float s = b_inst[i];
#pragma unroll
        for (int cc = 0; cc < 8; ++cc)
            s += part_m[((size_t)(cc*NI + i)*NB + b)*NHW + n0 + nl];
        lg[i][nl] = s;
    }
    __syncthreads();
    {
        int nl = tid & 31, i = tid >> 5;
        float mx = lg[0][nl];
#pragma unroll
        for (int k = 1; k < NI; ++k) mx = fmaxf(mx, lg[k][nl]);
        float ssum = 0.f;
#pragma unroll
        for (int k = 0; k < NI; ++k) ssum += __expf(lg[k][nl] - mx);
        float mv = __expf(lg[i][nl] - mx) / ssum;
        m_s[i][nl] = mv;
        masks[((size_t)i*NB + b)*NHW + n0 + nl] = mv;
    }
    __syncthreads();
    int c = tid;
    float bqv = bq[c], bkv = bk[c];
    const f16* gq = Gqt + ((size_t)b*NHW + n0)*NC + c;
    const f16* gk = Gkt + ((size_t)b*NHW + n0)*NC + c;
    float aq[NI] = {}, ak[NI] = {};
#pragma unroll
    for (int t4 = 0; t4 < 32; t4 += 4) {
        float g1[4], g2[4];
#pragma unroll
        for (int r = 0; r < 4; ++r) {
            g1[r] = (float)gq[(size_t)(t4 + r)*NC];
            g2[r] = (float)gk[(size_t)(t4 + r)*NC];
        }
#pragma unroll
        for (int i = 0; i < NI; ++i) {
            float4 mm4 = *(const float4*)&m_s[i][t4];
            float mm[4] = {mm4.x, mm4.y, mm4.z, mm4.w};
#pragma unroll
            for (int r = 0; r < 4; ++r) {
                float e = fmaf(mm[r], g1[r], bqv); aq[i] = fmaf(e, e, aq[i]);
                e = fmaf(mm[r], g2[r], bkv);       ak[i] = fmaf(e, e, ak[i]);
            }
        }
    }
#pragma unroll
    for (int i = 0; i < NI; ++i) {
        part_nq[((size_t)(nc*NI + i)*NB + b)*NC + c] = aq[i];
        part_nk[((size_t)(nc*NI + i)*NB + b)*NC + c] = ak[i];
    }
}

// ---------------- K3b: finalize scales ----------------
__global__ __launch_bounds__(256) void k_norm_fin(
    const float* __restrict__ part_nq, const float* __restrict__ part_nk,
    float* __restrict__ scale_q, float* __restrict__ scale_k)
{
    int b = blockIdx.x, i = blockIdx.y, c = threadIdx.x;
    float sq = 0.f, sk = 0.f;
#pragma unroll
    for (int nc = 0; nc < 32; ++nc) {
        sq += part_nq[((size_t)(nc*NI + i)*NB + b)*NC + c];
        sk += part_nk[((size_t)(nc*NI + i)*NB + b)*NC + c];
    }
    scale_q[((size_t)i*NB + b)*NC + c] = 0.125f / fmaxf(sqrtf(sq), EPS);
    scale_k[((size_t)i*NB + b)*NC + c] = 1.0f   / fmaxf(sqrtf(sk), EPS);
}

// ---------------- K4: attention v13 — 8 waves x 1 instance (best-measured-total config, R7) ----------------
// Exact revert to the 203.3 µs configuration. 512 threads, wave w owns instance w, QBLK=32,
// KVBLK=64, permlane D->B exchange, no setprio, expf softmax. VGPR 64, occ ~38%.
// LDS 36864 = KH[2][64][64]@0 + VH[2][64][64]@16384 + MI[2][8][64]@32768; epilogue 4x9216B overlay.
__global__ __launch_bounds__(512,2) void k_attn13(
    const f16* __restrict__ Gqt, const f16* __restrict__ Gkt, const f16* __restrict__ Gv,
    const float* __restrict__ masks,
    const float* __restrict__ bq, const float* __restrict__ bv,
    const float* __restrict__ scale_q, const float* __restrict__ scale_k,
    float* __restrict__ out)
{
    __shared__ __align__(16) char lds[36864];
    f16*   KH = (f16*)lds;                  // buf stride 4096 f16
    f16*   VH = (f16*)(lds + 16384);        // buf stride 4096 f16
    float* MI = (float*)(lds + 32768);      // buf stride 512 f32

    int tid = threadIdx.x, bid = blockIdx.x;
    int b = bid & 7, qt = (bid >> 3) & 31, h = bid >> 8;
    int qt0 = qt*32, c0 = h*HD;
    int w = tid >> 6, lane = tid & 63, quad = lane >> 4, l15 = lane & 15;
    // wave w handles instance w

    // ---- hoisted raw Gq B-frags + q~ for instance w (mask/bias/scales folded) ----
    H8 graw[2][2];
    const f16* gqp = Gqt + ((size_t)b*NHW + qt0)*NC + c0;
#pragma unroll
    for (int qi = 0; qi < 2; ++qi)
#pragma unroll
        for (int ks = 0; ks < 2; ++ks)
            graw[qi][ks].u4 = *(const uint4*)(gqp + (size_t)(qi*16 + l15)*NC + ks*32 + quad*8);
    float mqf[2];
#pragma unroll
    for (int qi = 0; qi < 2; ++qi)
        mqf[qi] = masks[((size_t)w*NB + b)*NHW + qt0 + qi*16 + l15];
    H8 qa[2][2];   // [qi][ks]
#pragma unroll
    for (int ks = 0; ks < 2; ++ks) {
        int cb = c0 + ks*32 + quad*8;
        float4 bq0 = *(const float4*)(bq + cb);
        float4 bq1 = *(const float4*)(bq + cb + 4);
        const float* sqg = scale_q + ((size_t)w*NB + b)*NC;
        const float* skg = scale_k + ((size_t)w*NB + b)*NC;
        float4 s0 = *(const float4*)(sqg + cb);
        float4 s1 = *(const float4*)(sqg + cb + 4);
        float4 t0 = *(const float4*)(skg + cb);
        float4 t1 = *(const float4*)(skg + cb + 4);
        float ss[8] = {s0.x*t0.x*QSC, s0.y*t0.y*QSC, s0.z*t0.z*QSC, s0.w*t0.w*QSC,
                       s1.x*t1.x*QSC, s1.y*t1.y*QSC, s1.z*t1.z*QSC, s1.w*t1.w*QSC};
        float bb[8] = {bq0.x*ss[0], bq0.y*ss[1], bq0.z*ss[2], bq0.w*ss[3],
                       bq1.x*ss[4], bq1.y*ss[5], bq1.z*ss[6], bq1.w*ss[7]};
        __half2 sh[4], bh[4];
#pragma unroll
        for (int t = 0; t < 4; ++t) {
            sh[t] = __floats2half2_rn(ss[2*t], ss[2*t+1]);
            bh[t] = __floats2half2_rn(bb[2*t], bb[2*t+1]);
        }
#pragma unroll
        for (int qi = 0; qi < 2; ++qi) {
            __half2 mq2 = __float2half2_rn(mqf[qi]);
#pragma unroll
            for (int t = 0; t < 4; ++t)
                qa[qi][ks].h2[t] = __hfma2(mq2, __hmul2(graw[qi][ks].h2[t], sh[t]), bh[t]);
        }
    }

    // ---- staging lane constants (pre-swizzled global source, linear LDS dest; 512 threads) ----
    int kjr = tid >> 3, kdc = (tid & 7) ^ (kjr & 7);           // K: 64 j-rows x 8 chunks
    const f16* kgb = Gkt + (size_t)b*NHW*NC + c0 + kdc*8;      // + (jn+kjr)*NC
    int vcr = tid >> 3, vdc = (tid & 7) ^ (vcr & 7);           // V: 64 c-rows x 8 chunks
    const f16* vgb = Gv + ((size_t)(b*NC + c0 + vcr))*NHW + vdc*8;   // + jn
    const float* mgb = masks + ((size_t)(tid >> 4)*NB + b)*NHW + (tid & 15)*4;  // tid<128

    floatx4 acc[4][2];   // [cm][qi]
#pragma unroll
    for (int cm=0;cm<4;cm++)
#pragma unroll
        for (int qi=0;qi<2;qi++) { acc[cm][qi][0]=0.f; acc[cm][qi][1]=0.f;
                                   acc[cm][qi][2]=0.f; acc[cm][qi][3]=0.f; }
    float l[2] = {};

    // prologue: stage tile 0 -> buf 0 (async)
    gll16(kgb + (size_t)kjr*NC, KH + tid*8);
    gll16(vgb,                  VH + tid*8);
    if (tid < 128) gll16(mgb, MI + tid*4);
    __syncthreads();

    int p = 0;
    for (int j0 = 0; j0 < NHW; j0 += 64) {
        int jn = (j0 + 64) & (NHW - 1);
        // async stage next tile -> buf p^1
        gll16(kgb + (size_t)(jn + kjr)*NC, KH + (p^1)*4096 + tid*8);
        gll16(vgb + jn,                    VH + (p^1)*4096 + tid*8);
        if (tid < 128) gll16(mgb + jn, MI + (p^1)*512 + tid*4);

        const f16* kh = KH + p*4096;
        const f16* vh = VH + p*4096;
        const float* mi = MI + p*512;

        // ---- per 32-j half: QK -> softmax -> pb -> PV ----
#pragma unroll
        for (int half = 0; half < 2; ++half) {
            unsigned pw[2][2][2];   // [qi][jm2][pair]
#pragma unroll
            for (int jm2 = 0; jm2 < 2; ++jm2) {
                int jm = half*2 + jm2;
                int krow = jm*16 + l15;
                H8 ka0, ka1;
                ka0.u4 = *(const uint4*)&kh[krow*64 + ((quad       ^ (l15 & 7))*8)];
                ka1.u4 = *(const uint4*)&kh[krow*64 + (((4 + quad) ^ (l15 & 7))*8)];
                floatx4 s0 = {0.f,0.f,0.f,0.f}, s1 = {0.f,0.f,0.f,0.f};
                s0 = __builtin_amdgcn_mfma_f32_16x16x32_f16(ka0.h8, qa[0][0].h8, s0, 0, 0, 0);
                s0 = __builtin_amdgcn_mfma_f32_16x16x32_f16(ka1.h8, qa[0][1].h8, s0, 0, 0, 0);
                s1 = __builtin_amdgcn_mfma_f32_16x16x32_f16(ka0.h8, qa[1][0].h8, s1, 0, 0, 0);
                s1 = __builtin_amdgcn_mfma_f32_16x16x32_f16(ka1.h8, qa[1][1].h8, s1, 0, 0, 0);
                float4 mj4 = *(const float4*)&mi[w*64 + jm*16 + quad*4];
                float mj[4] = {mj4.x, mj4.y, mj4.z, mj4.w};
                float p0[4], p1[4];
#pragma unroll
                for (int r = 0; r < 4; ++r) {
                    float mq = mj[r]*QSCI;
                    float e0 = __expf(s0[r]*mq); l[0] += e0; p0[r] = e0*mj[r];
                    float e1 = __expf(s1[r]*mq); l[1] += e1; p1[r] = e1*mj[r];
                }
                PK k0, k1, k2, k3;
                k0.h2 = __floats2half2_rn(p0[0], p0[1]); k1.h2 = __floats2half2_rn(p0[2], p0[3]);
                k2.h2 = __floats2half2_rn(p1[0], p1[1]); k3.h2 = __floats2half2_rn(p1[2], p1[3]);
                pw[0][jm2][0] = k0.u; pw[0][jm2][1] = k1.u;
                pw[1][jm2][0] = k2.u; pw[1][jm2][1] = k3.u;
            }
            // D->B quad redistribution (v9-verified):
            // (u0,u2) = p16swap(p32swap(w0,w2)); (u1,u3) = p16swap(p32swap(w1,w3))
            H8 pb[2];
#pragma unroll
            for (int qi = 0; qi < 2; ++qi) {
                unsigned a = pw[qi][0][0], bx = pw[qi][0][1];
                unsigned c = pw[qi][1][0], d  = pw[qi][1][1];
                asm("v_permlane32_swap_b32 %0, %1" : "+v"(a),  "+v"(c));
                asm("v_permlane16_swap_b32 %0, %1" : "+v"(a),  "+v"(c));
                asm("v_permlane32_swap_b32 %0, %1" : "+v"(bx), "+v"(d));
                asm("v_permlane16_swap_b32 %0, %1" : "+v"(bx), "+v"(d));
                H8 t; t.u4.x = a; t.u4.y = bx; t.u4.z = c; t.u4.w = d;
                pb[qi] = t;
            }
            // PV for this half
#pragma unroll
            for (int cm = 0; cm < 4; ++cm) {
                H8 va;
                va.u4 = *(const uint4*)&vh[(cm*16 + l15)*64 + (((half*4 + quad) ^ (l15 & 7))*8)];
                acc[cm][0] = __builtin_amdgcn_mfma_f32_16x16x32_f16(va.h8, pb[0].h8, acc[cm][0], 0, 0, 0);
                acc[cm][1] = __builtin_amdgcn_mfma_f32_16x16x32_f16(va.h8, pb[1].h8, acc[cm][1], 0, 0, 0);
            }
        }
        __syncthreads();   // drains gll (next tile ready) + fences buffer reuse
        p ^= 1;
    }

    // ---- f = m_q/l (reduce over quads: lane bits 4,5) ----
    float f[2];
#pragma unroll
    for (int qi = 0; qi < 2; ++qi) {
        float lv = l[qi];
        lv += __shfl_xor(lv, 16, 64);
        lv += __shfl_xor(lv, 32, 64);
        f[qi] = mqf[qi] / lv;
    }
    // ---- cross-instance tree: 4 bufs (inst w & w+4 share buf w&3), then sum 4 ----
    float* rb = (float*)lds + (size_t)(w & 3)*2304;   // 9216 B per buf
    if (w < 4) {
#pragma unroll
        for (int cm = 0; cm < 4; ++cm)
#pragma unroll
            for (int qi = 0; qi < 2; ++qi)
#pragma unroll
                for (int r = 0; r < 4; ++r)
                    rb[(cm*16 + quad*4 + r)*36 + qi*16 + l15] = f[qi]*acc[cm][qi][r];
    }
    __syncthreads();
    if (w >= 4) {
#pragma unroll
        for (int cm = 0; cm < 4; ++cm)
#pragma unroll
            for (int qi = 0; qi < 2; ++qi)
#pragma unroll
                for (int r = 0; r < 4; ++r)
                    rb[(cm*16 + quad*4 + r)*36 + qi*16 + l15] += f[qi]*acc[cm][qi][r];
    }
    __syncthreads();
    int cc2 = tid >> 3, qg = (tid & 7)*4;
    float bvv = bv[c0 + cc2];
    const float* b0 = (const float*)lds;
    float4 v0 = *(const float4*)&b0[cc2*36 + qg];
    float4 v1 = *(const float4*)&b0[2304 + cc2*36 + qg];
    float4 v2 = *(const float4*)&b0[4608 + cc2*36 + qg];
    float4 v3 = *(const float4*)&b0[6912 + cc2*36 + qg];
    float4 v;
    v.x = v0.x + v1.x + v2.x + v3.x + bvv;
    v.y = v0.y + v1.y + v2.y + v3.y + bvv;
    v.z = v0.z + v1.z + v2.z + v3.z + bvv;
    v.w = v0.w + v1.w + v2.w + v3.w + bvv;
    *(float4*)(out + ((size_t)(b*NC + c0 + cc2))*NHW + qt0 + qg) = v;
}

extern "C" void kernel_launch(void* const* d_in, const int* in_sizes, int n_in,
                              void* d_out, int out_size, void* d_ws, size_t ws_size,
                              hipStream_t stream)
{
    const float* x      = (const float*)d_in[0];
    const float* w_inst = (const float*)d_in[1];
    const float* b_inst = (const float*)d_in[2];
    const float* wq = (const float*)d_in[3];
    const float* bq = (const float*)d_in[4];
    const float* wk = (const float*)d_in[5];
    const float* bk = (const float*)d_in[6];
    const float* wv = (const float*)d_in[7];
    const float* bv = (const float*)d_in[8];
    float* out = (float*)d_out;

    float* masks   = (float*)d_ws;                        // 8*8*1024 f32
    float* scale_q = masks + (size_t)NI*NB*NHW;           // 8*8*256
    float* scale_k = scale_q + (size_t)NI*NB*NC;
    f16*   Gqt     = (f16*)(scale_k + (size_t)NI*NB*NC);  // [b][n][c] f16
    f16*   Gkt     = Gqt + (size_t)NB*NHW*NC;             // [b][n][c] f16
    f16*   Gv      = Gkt + (size_t)NB*NHW*NC;             // [b][c][n] f16
    f16*   xt      = Gv + (size_t)NB*NC*NHW;              // [b][n][c] f16
    float* part_m  = (float*)(xt + (size_t)NB*NHW*NC);    // 8*8*8*1024
    float* part_nq = part_m + (size_t)8*NI*NB*NHW;        // 32*8*8*256
    float* part_nk = part_nq + (size_t)32*NI*NB*NC;

    k_mask_part<<<dim3(4, NB, 8), 256, 0, stream>>>(x, w_inst, part_m, xt);
    k_gemm_mfma<<<dim3(8, 4, 24), 256, 0, stream>>>(xt, wq, wk, wv, Gqt, Gkt, Gv);
    k_norm_mask<<<dim3(32, NB), 256, 0, stream>>>(part_m, b_inst, Gqt, Gkt, bq, bk,
                                                  masks, part_nq, part_nk);
    k_norm_fin<<<dim3(NB, NI), 256, 0, stream>>>(part_nq, part_nk, scale_q, scale_k);
    k_attn13<<<dim3(1024), 512, 0, stream>>>(Gqt, Gkt, Gv, masks, bq, bv,
                                             scale_q, scale_k, out);
}